// Round 12
// baseline (529.498 us; speedup 1.0000x reference)
//
#include <hip/hip_runtime.h>

typedef unsigned short u16;
typedef __bf16 bf16x8 __attribute__((ext_vector_type(8)));
typedef float f32x4 __attribute__((ext_vector_type(4)));

__device__ __forceinline__ float b2f(u16 u) {
  unsigned int x = ((unsigned int)u) << 16;
  float f;
  __builtin_memcpy(&f, &x, 4);
  return f;
}
__device__ __forceinline__ u16 f2b(float f) {
  unsigned int x;
  __builtin_memcpy(&x, &f, 4);
  unsigned int r = x + 0x7FFFu + ((x >> 16) & 1u);
  return (u16)(r >> 16);
}
static inline unsigned int f2b_host(float f) {
  unsigned int x;
  __builtin_memcpy(&x, &f, 4);
  unsigned int r = x + 0x7FFFu + ((x >> 16) & 1u);
  return r >> 16;
}

// Async global->LDS, 16B per lane. LDS dest = wave-uniform base + lane*16.
__device__ __forceinline__ void gl_lds16(const u16* g, u16* l) {
  __builtin_amdgcn_global_load_lds(
      (const __attribute__((address_space(1))) void*)g,
      (__attribute__((address_space(3))) void*)l, 16, 0, 0);
}

// ---------------------------------------------------------------------------
// Diagnostic fill: pattern decodes to ~C as bf16 pair AND as fp32.
// ---------------------------------------------------------------------------
__global__ __launch_bounds__(256) void fill_diag(unsigned int* __restrict__ p,
                                                 long n4, unsigned int pat) {
  long i = (long)blockIdx.x * 256 + threadIdx.x;
  const long stride = (long)gridDim.x * 256;
  for (; i < n4; i += stride) p[i] = pat;
}

// ---------------------------------------------------------------------------
// Dtype sniff (bf16 N(0,1) never has exponent>=0x90; fp32-as-u16 does ~44%)
// + zero the stats accumulators (ws is 0xAA-poisoned before every call).
// ---------------------------------------------------------------------------
__global__ __launch_bounds__(256) void detect_dtype(const u16* __restrict__ text,
                                                    int* __restrict__ flag,
                                                    float* __restrict__ stats) {
  __shared__ int red[4];
  const int t = threadIdx.x;
  if (t < 128) stats[t] = 0.f;
  int c = 0;
#pragma unroll
  for (int j = 0; j < 8; j++) {
    u16 u = text[t * 8 + j];
    int e = (u >> 7) & 0xFF;
    c += (e >= 0x90);
  }
#pragma unroll
  for (int off = 32; off; off >>= 1) c += __shfl_xor(c, off);
  if ((t & 63) == 0) red[t >> 6] = c;
  __syncthreads();
  if (t == 0) flag[0] = (red[0] + red[1] + red[2] + red[3] >= 16) ? 1 : 0;
}

// ---------------------------------------------------------------------------
// Canonicalize input slices to workspace copies (either src dtype).
// fmt=0: bf16 out. fmt=1: f32 out (used for conv weights).
// ---------------------------------------------------------------------------
struct Cvt {
  const void* s;
  u16* d;
  long soff;
  int n;
  int fmt;
};
struct Cvt16 {
  Cvt c[14];
};
__global__ __launch_bounds__(256) void convert16(Cvt16 args, const int* __restrict__ flag) {
  const Cvt cc = args.c[blockIdx.y];
  const int i8 = (blockIdx.x * 256 + threadIdx.x) * 8;
  if (i8 >= cc.n) return;
  float f[8];
  if (flag[0]) {
    const float* s = (const float*)cc.s + cc.soff + i8;
    float4 a = *(const float4*)s;
    float4 b = *(const float4*)(s + 4);
    f[0] = a.x; f[1] = a.y; f[2] = a.z; f[3] = a.w;
    f[4] = b.x; f[5] = b.y; f[6] = b.z; f[7] = b.w;
  } else {
    uint4 r = *(const uint4*)((const u16*)cc.s + cc.soff + i8);
    u16 v[8];
    __builtin_memcpy(v, &r, 16);
#pragma unroll
    for (int j = 0; j < 8; j++) f[j] = b2f(v[j]);
  }
  if (cc.fmt) {
    float* d = (float*)cc.d + i8;
    float4 o0 = {f[0], f[1], f[2], f[3]};
    float4 o1 = {f[4], f[5], f[6], f[7]};
    *(float4*)d = o0;
    *(float4*)(d + 4) = o1;
  } else {
    u16 o[8];
#pragma unroll
    for (int j = 0; j < 8; j++) o[j] = f2b(f[j]);
    uint4 pk;
    __builtin_memcpy(&pk, o, 16);
    *(uint4*)(cc.d + i8) = pk;
  }
}

// ---------------------------------------------------------------------------
// NT GEMM: C[zc][m][n] = scale * sum_k A[za'][m][k] * B[zl][n][k] (+ bias[n]).
// zl = blockIdx.z (chunk-local), zg = zl + z0 (global).
// A offset: ((za>>zshA)&zmaskA)*sA, za = aglob?zg:zl. B: zl*sB (always local).
// C: base + zc*sC, zc = cglob?zg:zl. stats indexed by zg.
// BK=64 staging: global_load_lds width=16 into a unit-swizzled LDS tile.
//   Tile = 128 rows x 64 k (u16) = 1024 x 16B units.
//   swz(m) = ((m>>1)&3) | ((m&1)<<2)  -- PARITY-MIXING: row parity feeds
//   bit 2 of the perm so 8 consecutive lanes hit 8 distinct bank-quads
//   (m*128B stride alone contributes 0 to bank; this restores the property
//   that made the BK=32 layout conflict-free. r11 measured 4.7M conflicts
//   with swz=(m>>1)&7; this fixes it).
//   Unit (m,kc) lives at slot m*8 + ((kc + swz(m)) & 7)   [kc = k/8].
//   Staging: region (g*4+wv) covers rows r0=(g*4+wv)*8..+8; lane l fetches
//   global (row=r0+(l>>3), kc=((l&7)-swz(row))&7) -> LDS base+l*16.
//   Per 8-lane group = one full 128B row (permuted) -> coalesced.
// 2 barriers per 64-K step (32 MFMA per step, in two kk halves).
// 128x128 tile, 256 thr = 4 waves, mfma_f32_16x16x32_bf16.
// ---------------------------------------------------------------------------
template <int OUT_BF16, int ADD_BIAS, int DO_STATS>
__global__ __launch_bounds__(256) void gemm_nt(
    const u16* __restrict__ A, const u16* __restrict__ B, void* __restrict__ Cv,
    const u16* __restrict__ bias, int lda, int ldb, int ldc, int K,
    long sA, int zshA, int zmaskA, long sB, long sC, long base, float scale,
    const int* __restrict__ oflag, float* __restrict__ stats,
    int z0, int aglob, int cglob) {
  __shared__ u16 As[8192];
  __shared__ u16 Bs[8192];
  __shared__ float redS[4], redQ[4];
  const int t = threadIdx.x;
  const int zl = blockIdx.z;
  const int zg = zl + z0;
  const int za = aglob ? zg : zl;
  const int zc = cglob ? zg : zl;
  A += (long)((za >> zshA) & zmaskA) * sA;
  B += (long)zl * sB;
  const int bm = blockIdx.y * 128;
  const int bn = blockIdx.x * 128;
  const int lane = t & 63;
  const int wv = t >> 6;
  const int wm = (wv & 1) * 64;
  const int wn = (wv >> 1) * 64;
  const int lr = lane & 15;
  const int lq = lane >> 4;

  // staging: instruction g covers region (g*4+wv); lane l -> row, swizzled kc
  const u16* pa[4];
  const u16* pb[4];
  u16* lA[4];
  u16* lB[4];
#pragma unroll
  for (int g = 0; g < 4; g++) {
    const int reg = g * 4 + wv;
    const int row = reg * 8 + (lane >> 3);
    const int sw = (((row >> 1) & 3) | ((row & 1) << 2));
    const int kc = (((lane & 7) - sw) & 7) * 8;
    pa[g] = A + (size_t)(bm + row) * lda + kc;
    pb[g] = B + (size_t)(bn + row) * ldb + kc;
    lA[g] = &As[reg * 512];
    lB[g] = &Bs[reg * 512];
  }

  // fragment LDS addresses (K-invariant), two kk-halves
  const u16* aptr[4][2];
  const u16* bptr[4][2];
#pragma unroll
  for (int i = 0; i < 4; i++) {
    const int m = wm + i * 16 + lr;
    const int pm = ((m >> 1) & 3) | ((m & 1) << 2);
    aptr[i][0] = &As[(m * 8 + ((lq + pm) & 7)) * 8];
    aptr[i][1] = &As[(m * 8 + ((lq + 4 + pm) & 7)) * 8];
    const int n = wn + i * 16 + lr;
    const int pn = ((n >> 1) & 3) | ((n & 1) << 2);
    bptr[i][0] = &Bs[(n * 8 + ((lq + pn) & 7)) * 8];
    bptr[i][1] = &Bs[(n * 8 + ((lq + 4 + pn) & 7)) * 8];
  }

  f32x4 acc[4][4];
#pragma unroll
  for (int i = 0; i < 4; i++)
#pragma unroll
    for (int j = 0; j < 4; j++) acc[i][j] = (f32x4){0.f, 0.f, 0.f, 0.f};

  for (int k0 = 0; k0 < K; k0 += 64) {
#pragma unroll
    for (int g = 0; g < 4; g++) {
      gl_lds16(pa[g] + k0, lA[g]);
      gl_lds16(pb[g] + k0, lB[g]);
    }
    __syncthreads();
#pragma unroll
    for (int h = 0; h < 2; h++) {
      bf16x8 af[4], bfr[4];
#pragma unroll
      for (int i = 0; i < 4; i++) af[i] = *(const bf16x8*)aptr[i][h];
#pragma unroll
      for (int j = 0; j < 4; j++) bfr[j] = *(const bf16x8*)bptr[j][h];
#pragma unroll
      for (int i = 0; i < 4; i++)
#pragma unroll
        for (int j = 0; j < 4; j++)
          acc[i][j] = __builtin_amdgcn_mfma_f32_16x16x32_bf16(af[i], bfr[j], acc[i][j], 0, 0, 0);
    }
    __syncthreads();
  }

  int f32o = OUT_BF16 ? 0 : 1;
  if (oflag) f32o = oflag[0];
  u16* Cb = (u16*)Cv + base + (long)zc * sC;
  float* Cf = (float*)Cv + base + (long)zc * sC;
  float ls = 0.f, lsq = 0.f;
#pragma unroll
  for (int i = 0; i < 4; i++) {
    const int gm0 = bm + wm + i * 16 + lq * 4;
#pragma unroll
    for (int j = 0; j < 4; j++) {
      const int gn = bn + wn + j * 16 + lr;
      float bv = 0.f;
      if (ADD_BIAS) bv = b2f(bias[gn]);
#pragma unroll
      for (int r = 0; r < 4; r++) {
        float v = acc[i][j][r] * scale + bv;
        if (DO_STATS) {
          ls += v;
          lsq += v * v;
        }
        if (f32o)
          Cf[(size_t)(gm0 + r) * ldc + gn] = v;
        else
          Cb[(size_t)(gm0 + r) * ldc + gn] = f2b(v);
      }
    }
  }
  if (DO_STATS) {
#pragma unroll
    for (int off = 32; off; off >>= 1) {
      ls += __shfl_xor(ls, off);
      lsq += __shfl_xor(lsq, off);
    }
    if (lane == 0) {
      redS[wv] = ls;
      redQ[wv] = lsq;
    }
    __syncthreads();
    if (t == 0) {
      atomicAdd(&stats[zg * 2 + 0], redS[0] + redS[1] + redS[2] + redS[3]);
      atomicAdd(&stats[zg * 2 + 1], redQ[0] + redQ[1] + redQ[2] + redQ[3]);
    }
  }
}

// ---------------------------------------------------------------------------
// Flag-aware batched transpose of the embs: global z = z0+blockIdx.z selects
// [br][b]; output chunk-local [zl][1024][384] bf16. 64x64 LDS tiles.
// ---------------------------------------------------------------------------
struct Ptr4 {
  const void* p[4];
};
__global__ __launch_bounds__(256) void transpose_any4(Ptr4 in4, u16* __restrict__ out,
                                                      const int* __restrict__ flag,
                                                      int z0) {
  __shared__ u16 tile[64][72];
  const int t = threadIdx.x;
  const int zl = blockIdx.z;
  const int zg = zl + z0;
  const int br = zg >> 4, b = zg & 15;
  const long ebase = (long)b * 393216;
  const int r0 = blockIdx.y * 64;
  const int c0 = blockIdx.x * 64;
  const int isf32 = flag[0];
#pragma unroll
  for (int j = 0; j < 2; j++) {
    int idx = t + 256 * j;
    int r = idx >> 3, c8 = (idx & 7) << 3;
    u16 v[8];
    if (isf32) {
      const float* in = (const float*)in4.p[br] + ebase + (size_t)(r0 + r) * 1024 + c0 + c8;
      float4 a = *(const float4*)in;
      float4 bb = *(const float4*)(in + 4);
      v[0] = f2b(a.x); v[1] = f2b(a.y); v[2] = f2b(a.z); v[3] = f2b(a.w);
      v[4] = f2b(bb.x); v[5] = f2b(bb.y); v[6] = f2b(bb.z); v[7] = f2b(bb.w);
    } else {
      const u16* in = (const u16*)in4.p[br] + ebase + (size_t)(r0 + r) * 1024 + c0 + c8;
      uint4 rr = *(const uint4*)in;
      __builtin_memcpy(v, &rr, 16);
    }
    __builtin_memcpy(&tile[r][c8], v, 16);
  }
  __syncthreads();
#pragma unroll
  for (int j = 0; j < 2; j++) {
    int idx = t + 256 * j;
    int c = idx >> 3, r8 = (idx & 7) << 3;
    u16 v[8];
#pragma unroll
    for (int jj = 0; jj < 8; jj++) v[jj] = tile[r8 + jj][c];
    uint4 pk;
    __builtin_memcpy(&pk, v, 16);
    *(uint4*)&out[(size_t)zl * 393216 + (size_t)(c0 + c) * 384 + r0 + r8] = pk;
  }
}

// ---------------------------------------------------------------------------
// bf16 transpose: in [zl][384][1024] -> out [zl][1024][384] (chunk-local)
// ---------------------------------------------------------------------------
__global__ __launch_bounds__(256) void transpose_bf16(const u16* __restrict__ in,
                                                      u16* __restrict__ out) {
  __shared__ u16 tile[64][72];
  const int t = threadIdx.x;
  in += (size_t)blockIdx.z * 393216;
  out += (size_t)blockIdx.z * 393216;
  const int r0 = blockIdx.y * 64;
  const int c0 = blockIdx.x * 64;
#pragma unroll
  for (int j = 0; j < 2; j++) {
    int idx = t + 256 * j;
    int r = idx >> 3, c8 = (idx & 7) << 3;
    *(uint4*)&tile[r][c8] = *(const uint4*)&in[(size_t)(r0 + r) * 1024 + c0 + c8];
  }
  __syncthreads();
#pragma unroll
  for (int j = 0; j < 2; j++) {
    int idx = t + 256 * j;
    int c = idx >> 3, r8 = (idx & 7) << 3;
    u16 v[8];
#pragma unroll
    for (int jj = 0; jj < 8; jj++) v[jj] = tile[r8 + jj][c];
    uint4 pk;
    __builtin_memcpy(&pk, v, 16);
    *(uint4*)&out[(size_t)(c0 + c) * 384 + r0 + r8] = pk;
  }
}

// ---------------------------------------------------------------------------
// bf16 transpose of P: in [zl][384][384] -> out [zl][384][384]
// ---------------------------------------------------------------------------
__global__ __launch_bounds__(256) void transpose_b384(const u16* __restrict__ in,
                                                      u16* __restrict__ out) {
  __shared__ u16 tile[64][72];
  const int t = threadIdx.x;
  in += (size_t)blockIdx.z * 147456;
  out += (size_t)blockIdx.z * 147456;
  const int r0 = blockIdx.y * 64;
  const int c0 = blockIdx.x * 64;
#pragma unroll
  for (int j = 0; j < 2; j++) {
    int idx = t + 256 * j;
    int r = idx >> 3, c8 = (idx & 7) << 3;
    *(uint4*)&tile[r][c8] = *(const uint4*)&in[(size_t)(r0 + r) * 384 + c0 + c8];
  }
  __syncthreads();
#pragma unroll
  for (int j = 0; j < 2; j++) {
    int idx = t + 256 * j;
    int c = idx >> 3, r8 = (idx & 7) << 3;
    u16 v[8];
#pragma unroll
    for (int jj = 0; jj < 8; jj++) v[jj] = tile[r8 + jj][c];
    uint4 pk;
    __builtin_memcpy(&pk, v, 16);
    *(uint4*)&out[(size_t)(c0 + c) * 384 + r0 + r8] = pk;
  }
}

// ---------------------------------------------------------------------------
// In-place row L2-norm on bf16 [rows][1024] (torch F.normalize semantics)
// ---------------------------------------------------------------------------
__global__ __launch_bounds__(256) void l2norm_rows_bf16(u16* __restrict__ Q) {
  __shared__ float red[4];
  u16* row = Q + (size_t)blockIdx.x * 1024;
  const int t = threadIdx.x;
  uint2 r = *(const uint2*)(row + t * 4);
  u16 v[4];
  __builtin_memcpy(v, &r, 8);
  float f[4] = {b2f(v[0]), b2f(v[1]), b2f(v[2]), b2f(v[3])};
  float s = f[0] * f[0] + f[1] * f[1] + f[2] * f[2] + f[3] * f[3];
#pragma unroll
  for (int off = 32; off; off >>= 1) s += __shfl_xor(s, off);
  if ((t & 63) == 0) red[t >> 6] = s;
  __syncthreads();
  float tot = red[0] + red[1] + red[2] + red[3];
  float inv = 1.f / fmaxf(sqrtf(tot), 1e-12f);
  u16 o[4] = {f2b(f[0] * inv), f2b(f[1] * inv), f2b(f[2] * inv), f2b(f[3] * inv)};
  unsigned long long pk;
  __builtin_memcpy(&pk, o, 8);
  *(unsigned long long*)(row + t * 4) = pk;
}

// ---------------------------------------------------------------------------
// Grouped 3x3 conv, paired outputs, zero-padded LDS tile (no bounds checks).
// Tile p[2][34][34] f32 (stride 34: 2-way bank aliasing = free). Thread owns
// a horizontal 4-px strip (y=t>>3, x0=(t&7)*4): 6-value row window reused
// across dx -> 36 LDS reads + 144 FMA, zero branches. f32 weights (uniform
// s-loads). 8B packed stores. kv==0 fuses plane L2-norm.
// grid (192, Z, 2). Weight branch = (z0+zl)>>4.
// ---------------------------------------------------------------------------
__global__ __launch_bounds__(256) void gconv3x3(
    const u16* __restrict__ kvpre, const float* __restrict__ kwf,
    const float* __restrict__ vwf, u16* __restrict__ outK,
    u16* __restrict__ outV, int z0) {
  __shared__ float p[2][1156];  // 34*34
  __shared__ float redA[4], redB[4];
  const int o0 = blockIdx.x * 2;
  const int zl = blockIdx.y;
  const int kv = blockIdx.z;
  const int t = threadIdx.x;
  const int br = (z0 + zl) >> 4;
  const u16* in = kvpre + ((size_t)zl * 768 + kv * 384 + o0) * 1024;
  const float* wp = (kv ? vwf : kwf) + br * 6912 + o0 * 18;
  u16* out = (kv ? outV : outK) + ((size_t)zl * 384 + o0) * 1024;

  // zero-fill both padded tiles (halo stays 0 = SAME padding)
  {
    float* pf = &p[0][0];
    for (int i = t; i < 2312; i += 256) pf[i] = 0.f;
  }
  __syncthreads();

  const int y = t >> 3, x0 = (t & 7) * 4;
  {
    uint2 ra = *(const uint2*)(in + t * 4);
    uint2 rb = *(const uint2*)(in + 1024 + t * 4);
    u16 va[4], vb[4];
    __builtin_memcpy(va, &ra, 8);
    __builtin_memcpy(vb, &rb, 8);
    float* d0 = &p[0][(y + 1) * 34 + x0 + 1];
    float* d1 = &p[1][(y + 1) * 34 + x0 + 1];
#pragma unroll
    for (int j = 0; j < 4; j++) {
      d0[j] = b2f(va[j]);
      d1[j] = b2f(vb[j]);
    }
  }
  float w[36];
#pragma unroll
  for (int j = 0; j < 36; j++) w[j] = wp[j];
  __syncthreads();

  float oa[4] = {0.f, 0.f, 0.f, 0.f};
  float ob[4] = {0.f, 0.f, 0.f, 0.f};
#pragma unroll
  for (int ch = 0; ch < 2; ch++) {
#pragma unroll
    for (int dy = 0; dy < 3; dy++) {
      const float* row = &p[ch][(y + dy) * 34 + x0];
      float r[6];
#pragma unroll
      for (int j = 0; j < 6; j++) r[j] = row[j];
#pragma unroll
      for (int dx = 0; dx < 3; dx++) {
        const float wA = w[ch * 9 + dy * 3 + dx];
        const float wB = w[18 + ch * 9 + dy * 3 + dx];
#pragma unroll
        for (int i = 0; i < 4; i++) {
          oa[i] += wA * r[i + dx];
          ob[i] += wB * r[i + dx];
        }
      }
    }
  }

  float inva = 1.f, invb = 1.f;
  if (kv == 0) {
    float sa = oa[0] * oa[0] + oa[1] * oa[1] + oa[2] * oa[2] + oa[3] * oa[3];
    float sb = ob[0] * ob[0] + ob[1] * ob[1] + ob[2] * ob[2] + ob[3] * ob[3];
#pragma unroll
    for (int off = 32; off; off >>= 1) {
      sa += __shfl_xor(sa, off);
      sb += __shfl_xor(sb, off);
    }
    if ((t & 63) == 0) {
      redA[t >> 6] = sa;
      redB[t >> 6] = sb;
    }
    __syncthreads();
    float ta = redA[0] + redA[1] + redA[2] + redA[3];
    float tb = redB[0] + redB[1] + redB[2] + redB[3];
    inva = 1.f / fmaxf(sqrtf(ta), 1e-12f);
    invb = 1.f / fmaxf(sqrtf(tb), 1e-12f);
  }
  u16 pa[4], pb[4];
#pragma unroll
  for (int i = 0; i < 4; i++) {
    pa[i] = f2b(oa[i] * inva);
    pb[i] = f2b(ob[i] * invb);
  }
  unsigned long long ka, kb;
  __builtin_memcpy(&ka, pa, 8);
  __builtin_memcpy(&kb, pb, 8);
  *(unsigned long long*)(out + t * 4) = ka;
  *(unsigned long long*)(out + 1024 + t * 4) = kb;
}

// ---------------------------------------------------------------------------
// Softmax over rows of 384 after inst-norm scale (mean cancels). 1 wave/row.
// rstd computed inline from stats (finalize fused). Rows chunk-local.
// ---------------------------------------------------------------------------
__global__ __launch_bounds__(256) void softmax384(const float* __restrict__ S,
                                                  const float* __restrict__ stats,
                                                  u16* __restrict__ P, int z0) {
  const int row = blockIdx.x * 4 + (threadIdx.x >> 6);
  const int lane = threadIdx.x & 63;
  const int zg = z0 + row / 384;
  const float ssum = stats[2 * zg], ssq = stats[2 * zg + 1];
  const float mean = ssum * (1.f / 147456.f);
  const float var = ssq * (1.f / 147456.f) - mean * mean;
  const float rstd = 1.f / sqrtf(var + 1e-5f);
  const float* x = S + (size_t)row * 384;
  float v[6];
#pragma unroll
  for (int j = 0; j < 6; j++) v[j] = x[lane + 64 * j] * rstd;
  float m = v[0];
#pragma unroll
  for (int j = 1; j < 6; j++) m = fmaxf(m, v[j]);
#pragma unroll
  for (int off = 32; off; off >>= 1) m = fmaxf(m, __shfl_xor(m, off));
  float s = 0.f;
#pragma unroll
  for (int j = 0; j < 6; j++) {
    v[j] = __expf(v[j] - m);
    s += v[j];
  }
#pragma unroll
  for (int off = 32; off; off >>= 1) s += __shfl_xor(s, off);
  const float inv = 1.f / s;
  u16* out = P + (size_t)row * 384;
#pragma unroll
  for (int j = 0; j < 6; j++) out[lane + 64 * j] = f2b(v[j] * inv);
}

// ---------------------------------------------------------------------------
// B=16, C=384, H=W=32, HW=1024, TEXT=768.
// out = (po@P)@v with P from softmax(inst-norm(scale*q@k^T)).
// ws layout: fixed 17.9 MB = flag/stats + bf16 weights (wq,bq,mkv,po) +
//   f32 conv weights (kwf,vwf) + q16. Regions per z-chunk (Z pow2 1..64):
//   A=Z*0.75MB (xT->kAll->W), B=Z*1.5MB (kvpre->[vT|S->PT]), C=Z*0.75MB
//   (vAll->P16). text16 (9 MB, pre-loop) aliases regA.
//   need(Z)=17.9MB+max(Z*3MB,9MB).
// Gate failures encode into d_out: 1e6 bad args, 2e6 null ptr,
//   3e6+i*1.25e5 size mismatch at input i, 9e6 ws too small.
// ---------------------------------------------------------------------------
extern "C" void kernel_launch(void* const* d_in, const int* in_sizes, int n_in,
                              void* d_out, int out_size, void* d_ws, size_t ws_size,
                              hipStream_t stream) {
  char* ws = (char*)d_ws;
  const dim3 blk(256);

  const size_t bigOff = 17920000;
  auto need = [&](size_t Zs) {
    size_t c = Zs * 3145728;
    if (c < 9437184) c = 9437184;
    return bigOff + c;
  };
  auto diag = [&](float C) {
    unsigned int h = f2b_host(C);
    unsigned int pat = (h << 16) | h;
    long n4 = (long)out_size / 4;
    if (n4 < 1) n4 = 1;
    fill_diag<<<dim3(2048), blk, 0, stream>>>((unsigned int*)d_out, n4, pat);
  };

  // ---- validation gate --------------------------------------------------
  static const long elems[12] = {6291456, 6291456, 6291456, 6291456, 4718592,
                                 786432, 1024, 589824, 589824, 27648, 27648,
                                 589824};
  if (!(n_in >= 12) || !d_in || !in_sizes || !d_out || !d_ws) {
    diag(1.0e6f);
    return;
  }
  for (int i = 0; i < 12; i++) {
    if (!d_in[i]) {
      diag(2.0e6f);
      return;
    }
    long sz = in_sizes[i];
    if (sz != elems[i] && sz != elems[i] * 2 && sz != elems[i] * 4) {
      diag(3.0e6f + (float)i * 1.25e5f);
      return;
    }
  }
  if (ws_size < need(1)) {
    diag(9.0e6f);
    return;
  }
  // -----------------------------------------------------------------------

  int* flag = (int*)ws;
  float* stats = (float*)(ws + 256);  // 128 floats: [64]{sum,sumsq}
  char* wgt = ws + 2048;
  u16* wq16 = (u16*)wgt;                   // 1572864 B
  u16* bq16 = (u16*)(wgt + 1572864);       // 2048 B
  u16* mkv16 = (u16*)(wgt + 1574912);      // [4][768][384] = 2359296 B
  u16* po16 = (u16*)(wgt + 3934208);       // 1179648 B
  float* kwf = (float*)(wgt + 5113856);    // 110592 B (f32)
  float* vwf = (float*)(wgt + 5224448);    // 110592 B (f32)
  u16* q16 = (u16*)(ws + 5337088);         // 12582912 B, persistent

  int Z = 1;
  for (int cand = 64; cand >= 1; cand >>= 1) {
    if (ws_size >= need(cand)) {
      Z = cand;
      break;
    }
  }

  char* regA = ws + bigOff;                          // Z*786432 B
  char* regB = regA + (size_t)Z * 786432;            // Z*1572864 B
  char* regC = regB + (size_t)Z * 1572864;           // Z*786432 B

  u16* text16 = (u16*)regA;  // pre-loop only; spans regA.. (9437184 B)
  u16* xT = (u16*)regA;      // then kAll, then W
  u16* kAll = (u16*)regA;
  u16* W = (u16*)regA;       // Z*294912 B (within regA)
  u16* kvpre = (u16*)regB;   // then vT | (S -> PT)
  u16* vT = (u16*)regB;
  float* S = (float*)(regB + (size_t)Z * 786432);
  u16* PT = (u16*)(regB + (size_t)Z * 786432);  // overwrites S (dead)
  u16* vAll = (u16*)regC;    // then P16
  u16* P16 = (u16*)regC;

  const float scale = 0.05103103630798288f;  // 1/sqrt(384)

  detect_dtype<<<1, blk, 0, stream>>>((const u16*)d_in[4], flag, stats);

  // 14 conversion slices. mkv16 per-branch stride = 294912 ELEMENTS.
  Cvt16 ca{};
  int ci = 0;
  auto add = [&](const void* s, u16* d, long soff, int n, int fmt) {
    ca.c[ci].s = s; ca.c[ci].d = d; ca.c[ci].soff = soff; ca.c[ci].n = n;
    ca.c[ci].fmt = fmt; ci++;
  };
  add(d_in[4], text16, 0, 4718592, 0);
  add(d_in[5], wq16, 0, 786432, 0);
  add(d_in[6], bq16, 0, 1024, 0);
  for (int i = 0; i < 4; i++)
    add(d_in[7], mkv16 + (long)i * 294912, (long)i * 147456, 147456, 0);
  for (int i = 0; i < 4; i++)
    add(d_in[8], mkv16 + (long)i * 294912 + 147456, (long)i * 147456, 147456, 0);
  add(d_in[9], (u16*)kwf, 0, 27648, 1);
  add(d_in[10], (u16*)vwf, 0, 27648, 1);
  add(d_in[11], po16, 0, 589824, 0);
  convert16<<<dim3(2304, 14, 1), blk, 0, stream>>>(ca, flag);

  // q = l2norm(text @ wq^T + bq): M=6144, N=1024, K=768
  gemm_nt<1, 1, 0><<<dim3(8, 48, 1), blk, 0, stream>>>(
      text16, wq16, q16, bq16, 768, 768, 1024, 768, 0, 0, 0, 0, 0, 0, 1.f,
      nullptr, nullptr, 0, 0, 0);
  l2norm_rows_bf16<<<6144, blk, 0, stream>>>(q16);

  Ptr4 p4 = {{d_in[0], d_in[1], d_in[2], d_in[3]}};

  for (int z0 = 0; z0 < 64; z0 += Z) {
    // xT[zl] = emb[br][b]^T
    transpose_any4<<<dim3(16, 6, Z), blk, 0, stream>>>(p4, xT, flag, z0);

    // kvpre[zl] = [mk_br; mv_br] @ x[zl] : M=768, N=1024, K=384
    gemm_nt<1, 0, 0><<<dim3(8, 6, Z), blk, 0, stream>>>(
        mkv16, xT, kvpre, nullptr, 384, 384, 1024, 384, 294912, 4, 3, 393216,
        786432, 0, 1.f, nullptr, nullptr, z0, 1, 0);

    // grouped 3x3 conv (paired outputs, padded-LDS); k gets fused L2-norm
    gconv3x3<<<dim3(192, Z, 2), blk, 0, stream>>>(kvpre, kwf, vwf, kAll,
                                                  vAll, z0);

    // vT[zl] = v[zl]^T
    transpose_bf16<<<dim3(16, 6, Z), blk, 0, stream>>>(vAll, vT);

    // S[zl] = scale * q[b] @ k[zl]^T (M=N=384, K=1024) + fused stats
    gemm_nt<0, 0, 1><<<dim3(3, 3, Z), blk, 0, stream>>>(
        q16, kAll, S, nullptr, 1024, 1024, 384, 1024, 393216, 0, 15, 393216,
        147456, 0, scale, nullptr, stats, z0, 1, 0);

    // softmax(inst-norm(S)) -> P16 (rstd inline from stats)
    softmax384<<<Z * 96, blk, 0, stream>>>(S, stats, P16, z0);

    // PT[zl] = P[zl]^T (overwrites S, dead)
    transpose_b384<<<dim3(6, 6, Z), blk, 0, stream>>>(P16, PT);

    // W[zl] = po_br @ P[zl] : M=N=K=384 (NT, B=PT) -> bf16
    gemm_nt<1, 0, 0><<<dim3(3, 3, Z), blk, 0, stream>>>(
        po16, PT, W, nullptr, 384, 384, 384, 384, 147456, 4, 3, 147456,
        147456, 0, 1.f, nullptr, nullptr, z0, 1, 0);

    // out[zg] = W[zl] @ v[zl] : M=384, N=1024, K=384 (NT, B=vT); dtype per flag
    gemm_nt<0, 0, 0><<<dim3(8, 3, Z), blk, 0, stream>>>(
        W, vT, d_out, nullptr, 384, 384, 1024, 384, 147456, 0, 63, 393216,
        393216, 0, 1.f, flag, nullptr, z0, 0, 1);
  }
}

// Round 13
// 505.442 us; speedup vs baseline: 1.0476x; 1.0476x over previous
//
#include <hip/hip_runtime.h>

typedef unsigned short u16;
typedef __bf16 bf16x8 __attribute__((ext_vector_type(8)));
typedef float f32x4 __attribute__((ext_vector_type(4)));

__device__ __forceinline__ float b2f(u16 u) {
  unsigned int x = ((unsigned int)u) << 16;
  float f;
  __builtin_memcpy(&f, &x, 4);
  return f;
}
__device__ __forceinline__ u16 f2b(float f) {
  unsigned int x;
  __builtin_memcpy(&x, &f, 4);
  unsigned int r = x + 0x7FFFu + ((x >> 16) & 1u);
  return (u16)(r >> 16);
}
static inline unsigned int f2b_host(float f) {
  unsigned int x;
  __builtin_memcpy(&x, &f, 4);
  unsigned int r = x + 0x7FFFu + ((x >> 16) & 1u);
  return r >> 16;
}

// Async global->LDS, 16B per lane. LDS dest = wave-uniform base + lane*16.
__device__ __forceinline__ void gl_lds16(const u16* g, u16* l) {
  __builtin_amdgcn_global_load_lds(
      (const __attribute__((address_space(1))) void*)g,
      (__attribute__((address_space(3))) void*)l, 16, 0, 0);
}

// ---------------------------------------------------------------------------
// Diagnostic fill: pattern decodes to ~C as bf16 pair AND as fp32.
// ---------------------------------------------------------------------------
__global__ __launch_bounds__(256) void fill_diag(unsigned int* __restrict__ p,
                                                 long n4, unsigned int pat) {
  long i = (long)blockIdx.x * 256 + threadIdx.x;
  const long stride = (long)gridDim.x * 256;
  for (; i < n4; i += stride) p[i] = pat;
}

// ---------------------------------------------------------------------------
// Dtype sniff (bf16 N(0,1) never has exponent>=0x90; fp32-as-u16 does ~44%)
// + zero the stats accumulators (ws is 0xAA-poisoned before every call).
// ---------------------------------------------------------------------------
__global__ __launch_bounds__(256) void detect_dtype(const u16* __restrict__ text,
                                                    int* __restrict__ flag,
                                                    float* __restrict__ stats) {
  __shared__ int red[4];
  const int t = threadIdx.x;
  if (t < 128) stats[t] = 0.f;
  int c = 0;
#pragma unroll
  for (int j = 0; j < 8; j++) {
    u16 u = text[t * 8 + j];
    int e = (u >> 7) & 0xFF;
    c += (e >= 0x90);
  }
#pragma unroll
  for (int off = 32; off; off >>= 1) c += __shfl_xor(c, off);
  if ((t & 63) == 0) red[t >> 6] = c;
  __syncthreads();
  if (t == 0) flag[0] = (red[0] + red[1] + red[2] + red[3] >= 16) ? 1 : 0;
}

// ---------------------------------------------------------------------------
// Canonicalize input slices to workspace copies (either src dtype).
// fmt=0: bf16 out. fmt=1: f32 out (used for conv weights).
// ---------------------------------------------------------------------------
struct Cvt {
  const void* s;
  u16* d;
  long soff;
  int n;
  int fmt;
};
struct Cvt16 {
  Cvt c[14];
};
__global__ __launch_bounds__(256) void convert16(Cvt16 args, const int* __restrict__ flag) {
  const Cvt cc = args.c[blockIdx.y];
  const int i8 = (blockIdx.x * 256 + threadIdx.x) * 8;
  if (i8 >= cc.n) return;
  float f[8];
  if (flag[0]) {
    const float* s = (const float*)cc.s + cc.soff + i8;
    float4 a = *(const float4*)s;
    float4 b = *(const float4*)(s + 4);
    f[0] = a.x; f[1] = a.y; f[2] = a.z; f[3] = a.w;
    f[4] = b.x; f[5] = b.y; f[6] = b.z; f[7] = b.w;
  } else {
    uint4 r = *(const uint4*)((const u16*)cc.s + cc.soff + i8);
    u16 v[8];
    __builtin_memcpy(v, &r, 16);
#pragma unroll
    for (int j = 0; j < 8; j++) f[j] = b2f(v[j]);
  }
  if (cc.fmt) {
    float* d = (float*)cc.d + i8;
    float4 o0 = {f[0], f[1], f[2], f[3]};
    float4 o1 = {f[4], f[5], f[6], f[7]};
    *(float4*)d = o0;
    *(float4*)(d + 4) = o1;
  } else {
    u16 o[8];
#pragma unroll
    for (int j = 0; j < 8; j++) o[j] = f2b(f[j]);
    uint4 pk;
    __builtin_memcpy(&pk, o, 16);
    *(uint4*)(cc.d + i8) = pk;
  }
}

// ---------------------------------------------------------------------------
// NT GEMM: C[zc][m][n] = scale * sum_k A[za'][m][k] * B[zl][n][k] (+ bias[n]).
// zl = blockIdx.z (chunk-local), zg = zl + z0 (global).
// A offset: ((za>>zshA)&zmaskA)*sA, za = aglob?zg:zl. B: zl*sB (always local).
// C: base + zc*sC, zc = cglob?zg:zl. stats indexed by zg.
// Staging: global_load_lds width=16 into a unit-swizzled LDS tile.
//   Tile = 128 rows x 32 k (u16) = 512 x 16B units.
//   Unit (m,kc) lives at slot m*4 + ((kc + ((m>>1)&3)) & 3)  [kc = k/8].
// 128x128 tile, BK=32, 256 thr = 4 waves, mfma_f32_16x16x32_bf16.
// (r12 note: BK=64 variants measured 517/529 vs this template's 510; both
//  carried a 4.7M LDS bank-conflict signature insensitive to swizzle — the
//  BK=64 line is abandoned, this is the verified conflict-free anchor.)
// ---------------------------------------------------------------------------
template <int OUT_BF16, int ADD_BIAS, int DO_STATS>
__global__ __launch_bounds__(256) void gemm_nt(
    const u16* __restrict__ A, const u16* __restrict__ B, void* __restrict__ Cv,
    const u16* __restrict__ bias, int lda, int ldb, int ldc, int K,
    long sA, int zshA, int zmaskA, long sB, long sC, long base, float scale,
    const int* __restrict__ oflag, float* __restrict__ stats,
    int z0, int aglob, int cglob) {
  __shared__ u16 As[4096];
  __shared__ u16 Bs[4096];
  __shared__ float redS[4], redQ[4];
  const int t = threadIdx.x;
  const int zl = blockIdx.z;
  const int zg = zl + z0;
  const int za = aglob ? zg : zl;
  const int zc = cglob ? zg : zl;
  A += (long)((za >> zshA) & zmaskA) * sA;
  B += (long)zl * sB;
  const int bm = blockIdx.y * 128;
  const int bn = blockIdx.x * 128;
  const int lane = t & 63;
  const int wv = t >> 6;
  const int wm = (wv & 1) * 64;
  const int wn = (wv >> 1) * 64;
  const int lr = lane & 15;
  const int lq = lane >> 4;

  // staging addresses: wave wv handles chunks c0=2*wv and c0+1 of both tiles
  const int c0 = wv * 2;
  const int row0 = c0 * 16 + (lane >> 2);
  const int kcl = (((lane & 3) - ((lane >> 3) & 3)) & 3) * 8;
  const u16* pa0 = A + (size_t)(bm + row0) * lda + kcl;
  const u16* pa1 = pa0 + (size_t)16 * lda;
  const u16* pb0 = B + (size_t)(bn + row0) * ldb + kcl;
  const u16* pb1 = pb0 + (size_t)16 * ldb;
  u16* lA0 = &As[c0 * 512];
  u16* lA1 = &As[c0 * 512 + 512];
  u16* lB0 = &Bs[c0 * 512];
  u16* lB1 = &Bs[c0 * 512 + 512];

  // fragment LDS addresses (K-invariant)
  const u16* aptr[4];
  const u16* bptr[4];
#pragma unroll
  for (int i = 0; i < 4; i++) {
    const int m = wm + i * 16 + lr;
    aptr[i] = &As[(m * 4 + ((lq + ((m >> 1) & 3)) & 3)) * 8];
    const int n = wn + i * 16 + lr;
    bptr[i] = &Bs[(n * 4 + ((lq + ((n >> 1) & 3)) & 3)) * 8];
  }

  f32x4 acc[4][4];
#pragma unroll
  for (int i = 0; i < 4; i++)
#pragma unroll
    for (int j = 0; j < 4; j++) acc[i][j] = (f32x4){0.f, 0.f, 0.f, 0.f};

  for (int k0 = 0; k0 < K; k0 += 32) {
    gl_lds16(pa0 + k0, lA0);
    gl_lds16(pa1 + k0, lA1);
    gl_lds16(pb0 + k0, lB0);
    gl_lds16(pb1 + k0, lB1);
    __syncthreads();
    bf16x8 af[4], bfr[4];
#pragma unroll
    for (int i = 0; i < 4; i++) af[i] = *(const bf16x8*)aptr[i];
#pragma unroll
    for (int j = 0; j < 4; j++) bfr[j] = *(const bf16x8*)bptr[j];
#pragma unroll
    for (int i = 0; i < 4; i++)
#pragma unroll
      for (int j = 0; j < 4; j++)
        acc[i][j] = __builtin_amdgcn_mfma_f32_16x16x32_bf16(af[i], bfr[j], acc[i][j], 0, 0, 0);
    __syncthreads();
  }

  int f32o = OUT_BF16 ? 0 : 1;
  if (oflag) f32o = oflag[0];
  u16* Cb = (u16*)Cv + base + (long)zc * sC;
  float* Cf = (float*)Cv + base + (long)zc * sC;
  float ls = 0.f, lsq = 0.f;
#pragma unroll
  for (int i = 0; i < 4; i++) {
    const int gm0 = bm + wm + i * 16 + lq * 4;
#pragma unroll
    for (int j = 0; j < 4; j++) {
      const int gn = bn + wn + j * 16 + lr;
      float bv = 0.f;
      if (ADD_BIAS) bv = b2f(bias[gn]);
#pragma unroll
      for (int r = 0; r < 4; r++) {
        float v = acc[i][j][r] * scale + bv;
        if (DO_STATS) {
          ls += v;
          lsq += v * v;
        }
        if (f32o)
          Cf[(size_t)(gm0 + r) * ldc + gn] = v;
        else
          Cb[(size_t)(gm0 + r) * ldc + gn] = f2b(v);
      }
    }
  }
  if (DO_STATS) {
#pragma unroll
    for (int off = 32; off; off >>= 1) {
      ls += __shfl_xor(ls, off);
      lsq += __shfl_xor(lsq, off);
    }
    if (lane == 0) {
      redS[wv] = ls;
      redQ[wv] = lsq;
    }
    __syncthreads();
    if (t == 0) {
      atomicAdd(&stats[zg * 2 + 0], redS[0] + redS[1] + redS[2] + redS[3]);
      atomicAdd(&stats[zg * 2 + 1], redQ[0] + redQ[1] + redQ[2] + redQ[3]);
    }
  }
}

// ---------------------------------------------------------------------------
// Flag-aware batched transpose of the embs: global z = z0+blockIdx.z selects
// [br][b]; output chunk-local [zl][1024][384] bf16. 64x64 LDS tiles.
// ---------------------------------------------------------------------------
struct Ptr4 {
  const void* p[4];
};
__global__ __launch_bounds__(256) void transpose_any4(Ptr4 in4, u16* __restrict__ out,
                                                      const int* __restrict__ flag,
                                                      int z0) {
  __shared__ u16 tile[64][72];
  const int t = threadIdx.x;
  const int zl = blockIdx.z;
  const int zg = zl + z0;
  const int br = zg >> 4, b = zg & 15;
  const long ebase = (long)b * 393216;
  const int r0 = blockIdx.y * 64;
  const int c0 = blockIdx.x * 64;
  const int isf32 = flag[0];
#pragma unroll
  for (int j = 0; j < 2; j++) {
    int idx = t + 256 * j;
    int r = idx >> 3, c8 = (idx & 7) << 3;
    u16 v[8];
    if (isf32) {
      const float* in = (const float*)in4.p[br] + ebase + (size_t)(r0 + r) * 1024 + c0 + c8;
      float4 a = *(const float4*)in;
      float4 bb = *(const float4*)(in + 4);
      v[0] = f2b(a.x); v[1] = f2b(a.y); v[2] = f2b(a.z); v[3] = f2b(a.w);
      v[4] = f2b(bb.x); v[5] = f2b(bb.y); v[6] = f2b(bb.z); v[7] = f2b(bb.w);
    } else {
      const u16* in = (const u16*)in4.p[br] + ebase + (size_t)(r0 + r) * 1024 + c0 + c8;
      uint4 rr = *(const uint4*)in;
      __builtin_memcpy(v, &rr, 16);
    }
    __builtin_memcpy(&tile[r][c8], v, 16);
  }
  __syncthreads();
#pragma unroll
  for (int j = 0; j < 2; j++) {
    int idx = t + 256 * j;
    int c = idx >> 3, r8 = (idx & 7) << 3;
    u16 v[8];
#pragma unroll
    for (int jj = 0; jj < 8; jj++) v[jj] = tile[r8 + jj][c];
    uint4 pk;
    __builtin_memcpy(&pk, v, 16);
    *(uint4*)&out[(size_t)zl * 393216 + (size_t)(c0 + c) * 384 + r0 + r8] = pk;
  }
}

// ---------------------------------------------------------------------------
// bf16 transpose: in [zl][384][1024] -> out [zl][1024][384] (chunk-local)
// ---------------------------------------------------------------------------
__global__ __launch_bounds__(256) void transpose_bf16(const u16* __restrict__ in,
                                                      u16* __restrict__ out) {
  __shared__ u16 tile[64][72];
  const int t = threadIdx.x;
  in += (size_t)blockIdx.z * 393216;
  out += (size_t)blockIdx.z * 393216;
  const int r0 = blockIdx.y * 64;
  const int c0 = blockIdx.x * 64;
#pragma unroll
  for (int j = 0; j < 2; j++) {
    int idx = t + 256 * j;
    int r = idx >> 3, c8 = (idx & 7) << 3;
    *(uint4*)&tile[r][c8] = *(const uint4*)&in[(size_t)(r0 + r) * 1024 + c0 + c8];
  }
  __syncthreads();
#pragma unroll
  for (int j = 0; j < 2; j++) {
    int idx = t + 256 * j;
    int c = idx >> 3, r8 = (idx & 7) << 3;
    u16 v[8];
#pragma unroll
    for (int jj = 0; jj < 8; jj++) v[jj] = tile[r8 + jj][c];
    uint4 pk;
    __builtin_memcpy(&pk, v, 16);
    *(uint4*)&out[(size_t)(c0 + c) * 384 + r0 + r8] = pk;
  }
}

// ---------------------------------------------------------------------------
// bf16 transpose of P: in [zl][384][384] -> out [zl][384][384]
// ---------------------------------------------------------------------------
__global__ __launch_bounds__(256) void transpose_b384(const u16* __restrict__ in,
                                                      u16* __restrict__ out) {
  __shared__ u16 tile[64][72];
  const int t = threadIdx.x;
  in += (size_t)blockIdx.z * 147456;
  out += (size_t)blockIdx.z * 147456;
  const int r0 = blockIdx.y * 64;
  const int c0 = blockIdx.x * 64;
#pragma unroll
  for (int j = 0; j < 2; j++) {
    int idx = t + 256 * j;
    int r = idx >> 3, c8 = (idx & 7) << 3;
    *(uint4*)&tile[r][c8] = *(const uint4*)&in[(size_t)(r0 + r) * 384 + c0 + c8];
  }
  __syncthreads();
#pragma unroll
  for (int j = 0; j < 2; j++) {
    int idx = t + 256 * j;
    int c = idx >> 3, r8 = (idx & 7) << 3;
    u16 v[8];
#pragma unroll
    for (int jj = 0; jj < 8; jj++) v[jj] = tile[r8 + jj][c];
    uint4 pk;
    __builtin_memcpy(&pk, v, 16);
    *(uint4*)&out[(size_t)(c0 + c) * 384 + r0 + r8] = pk;
  }
}

// ---------------------------------------------------------------------------
// In-place row L2-norm on bf16 [rows][1024] (torch F.normalize semantics)
// ---------------------------------------------------------------------------
__global__ __launch_bounds__(256) void l2norm_rows_bf16(u16* __restrict__ Q) {
  __shared__ float red[4];
  u16* row = Q + (size_t)blockIdx.x * 1024;
  const int t = threadIdx.x;
  uint2 r = *(const uint2*)(row + t * 4);
  u16 v[4];
  __builtin_memcpy(v, &r, 8);
  float f[4] = {b2f(v[0]), b2f(v[1]), b2f(v[2]), b2f(v[3])};
  float s = f[0] * f[0] + f[1] * f[1] + f[2] * f[2] + f[3] * f[3];
#pragma unroll
  for (int off = 32; off; off >>= 1) s += __shfl_xor(s, off);
  if ((t & 63) == 0) red[t >> 6] = s;
  __syncthreads();
  float tot = red[0] + red[1] + red[2] + red[3];
  float inv = 1.f / fmaxf(sqrtf(tot), 1e-12f);
  u16 o[4] = {f2b(f[0] * inv), f2b(f[1] * inv), f2b(f[2] * inv), f2b(f[3] * inv)};
  unsigned long long pk;
  __builtin_memcpy(&pk, o, 8);
  *(unsigned long long*)(row + t * 4) = pk;
}

// ---------------------------------------------------------------------------
// Grouped 3x3 conv, paired outputs, zero-padded LDS tile (no bounds checks).
// Tile p[2][34][34] f32 (stride 34: 2-way bank aliasing = free). Thread owns
// a horizontal 4-px strip (y=t>>3, x0=(t&7)*4): 6-value row window reused
// across dx -> 36 LDS reads + 144 FMA, zero branches. f32 weights (uniform
// s-loads). 8B packed stores. kv==0 fuses plane L2-norm.
// grid (192, Z, 2). Weight branch = (z0+zl)>>4.
// ---------------------------------------------------------------------------
__global__ __launch_bounds__(256) void gconv3x3(
    const u16* __restrict__ kvpre, const float* __restrict__ kwf,
    const float* __restrict__ vwf, u16* __restrict__ outK,
    u16* __restrict__ outV, int z0) {
  __shared__ float p[2][1156];  // 34*34
  __shared__ float redA[4], redB[4];
  const int o0 = blockIdx.x * 2;
  const int zl = blockIdx.y;
  const int kv = blockIdx.z;
  const int t = threadIdx.x;
  const int br = (z0 + zl) >> 4;
  const u16* in = kvpre + ((size_t)zl * 768 + kv * 384 + o0) * 1024;
  const float* wp = (kv ? vwf : kwf) + br * 6912 + o0 * 18;
  u16* out = (kv ? outV : outK) + ((size_t)zl * 384 + o0) * 1024;

  // zero-fill both padded tiles (halo stays 0 = SAME padding)
  {
    float* pf = &p[0][0];
    for (int i = t; i < 2312; i += 256) pf[i] = 0.f;
  }
  __syncthreads();

  const int y = t >> 3, x0 = (t & 7) * 4;
  {
    uint2 ra = *(const uint2*)(in + t * 4);
    uint2 rb = *(const uint2*)(in + 1024 + t * 4);
    u16 va[4], vb[4];
    __builtin_memcpy(va, &ra, 8);
    __builtin_memcpy(vb, &rb, 8);
    float* d0 = &p[0][(y + 1) * 34 + x0 + 1];
    float* d1 = &p[1][(y + 1) * 34 + x0 + 1];
#pragma unroll
    for (int j = 0; j < 4; j++) {
      d0[j] = b2f(va[j]);
      d1[j] = b2f(vb[j]);
    }
  }
  float w[36];
#pragma unroll
  for (int j = 0; j < 36; j++) w[j] = wp[j];
  __syncthreads();

  float oa[4] = {0.f, 0.f, 0.f, 0.f};
  float ob[4] = {0.f, 0.f, 0.f, 0.f};
#pragma unroll
  for (int ch = 0; ch < 2; ch++) {
#pragma unroll
    for (int dy = 0; dy < 3; dy++) {
      const float* row = &p[ch][(y + dy) * 34 + x0];
      float r[6];
#pragma unroll
      for (int j = 0; j < 6; j++) r[j] = row[j];
#pragma unroll
      for (int dx = 0; dx < 3; dx++) {
        const float wA = w[ch * 9 + dy * 3 + dx];
        const float wB = w[18 + ch * 9 + dy * 3 + dx];
#pragma unroll
        for (int i = 0; i < 4; i++) {
          oa[i] += wA * r[i + dx];
          ob[i] += wB * r[i + dx];
        }
      }
    }
  }

  float inva = 1.f, invb = 1.f;
  if (kv == 0) {
    float sa = oa[0] * oa[0] + oa[1] * oa[1] + oa[2] * oa[2] + oa[3] * oa[3];
    float sb = ob[0] * ob[0] + ob[1] * ob[1] + ob[2] * ob[2] + ob[3] * ob[3];
#pragma unroll
    for (int off = 32; off; off >>= 1) {
      sa += __shfl_xor(sa, off);
      sb += __shfl_xor(sb, off);
    }
    if ((t & 63) == 0) {
      redA[t >> 6] = sa;
      redB[t >> 6] = sb;
    }
    __syncthreads();
    float ta = redA[0] + redA[1] + redA[2] + redA[3];
    float tb = redB[0] + redB[1] + redB[2] + redB[3];
    inva = 1.f / fmaxf(sqrtf(ta), 1e-12f);
    invb = 1.f / fmaxf(sqrtf(tb), 1e-12f);
  }
  u16 pa[4], pb[4];
#pragma unroll
  for (int i = 0; i < 4; i++) {
    pa[i] = f2b(oa[i] * inva);
    pb[i] = f2b(ob[i] * invb);
  }
  unsigned long long ka, kb;
  __builtin_memcpy(&ka, pa, 8);
  __builtin_memcpy(&kb, pb, 8);
  *(unsigned long long*)(out + t * 4) = ka;
  *(unsigned long long*)(out + 1024 + t * 4) = kb;
}

// ---------------------------------------------------------------------------
// Softmax over rows of 384 after inst-norm scale (mean cancels). 1 wave/row.
// rstd computed inline from stats (finalize fused). Rows chunk-local.
// ---------------------------------------------------------------------------
__global__ __launch_bounds__(256) void softmax384(const float* __restrict__ S,
                                                  const float* __restrict__ stats,
                                                  u16* __restrict__ P, int z0) {
  const int row = blockIdx.x * 4 + (threadIdx.x >> 6);
  const int lane = threadIdx.x & 63;
  const int zg = z0 + row / 384;
  const float ssum = stats[2 * zg], ssq = stats[2 * zg + 1];
  const float mean = ssum * (1.f / 147456.f);
  const float var = ssq * (1.f / 147456.f) - mean * mean;
  const float rstd = 1.f / sqrtf(var + 1e-5f);
  const float* x = S + (size_t)row * 384;
  float v[6];
#pragma unroll
  for (int j = 0; j < 6; j++) v[j] = x[lane + 64 * j] * rstd;
  float m = v[0];
#pragma unroll
  for (int j = 1; j < 6; j++) m = fmaxf(m, v[j]);
#pragma unroll
  for (int off = 32; off; off >>= 1) m = fmaxf(m, __shfl_xor(m, off));
  float s = 0.f;
#pragma unroll
  for (int j = 0; j < 6; j++) {
    v[j] = __expf(v[j] - m);
    s += v[j];
  }
#pragma unroll
  for (int off = 32; off; off >>= 1) s += __shfl_xor(s, off);
  const float inv = 1.f / s;
  u16* out = P + (size_t)row * 384;
#pragma unroll
  for (int j = 0; j < 6; j++) out[lane + 64 * j] = f2b(v[j] * inv);
}

// ---------------------------------------------------------------------------
// B=16, C=384, H=W=32, HW=1024, TEXT=768.
// out = (po@P)@v with P from softmax(inst-norm(scale*q@k^T)).
// ws layout: fixed 17.9 MB = flag/stats + bf16 weights (wq,bq,mkv,po) +
//   f32 conv weights (kwf,vwf) + q16. Regions per z-chunk (Z pow2 1..64):
//   A=Z*0.75MB (xT->kAll->W), B=Z*1.5MB (kvpre->[vT|S->PT]), C=Z*0.75MB
//   (vAll->P16). text16 (9 MB, pre-loop) aliases regA.
//   need(Z)=17.9MB+max(Z*3MB,9MB).
// Gate failures encode into d_out: 1e6 bad args, 2e6 null ptr,
//   3e6+i*1.25e5 size mismatch at input i, 9e6 ws too small.
// ---------------------------------------------------------------------------
extern "C" void kernel_launch(void* const* d_in, const int* in_sizes, int n_in,
                              void* d_out, int out_size, void* d_ws, size_t ws_size,
                              hipStream_t stream) {
  char* ws = (char*)d_ws;
  const dim3 blk(256);

  const size_t bigOff = 17920000;
  auto need = [&](size_t Zs) {
    size_t c = Zs * 3145728;
    if (c < 9437184) c = 9437184;
    return bigOff + c;
  };
  auto diag = [&](float C) {
    unsigned int h = f2b_host(C);
    unsigned int pat = (h << 16) | h;
    long n4 = (long)out_size / 4;
    if (n4 < 1) n4 = 1;
    fill_diag<<<dim3(2048), blk, 0, stream>>>((unsigned int*)d_out, n4, pat);
  };

  // ---- validation gate --------------------------------------------------
  static const long elems[12] = {6291456, 6291456, 6291456, 6291456, 4718592,
                                 786432, 1024, 589824, 589824, 27648, 27648,
                                 589824};
  if (!(n_in >= 12) || !d_in || !in_sizes || !d_out || !d_ws) {
    diag(1.0e6f);
    return;
  }
  for (int i = 0; i < 12; i++) {
    if (!d_in[i]) {
      diag(2.0e6f);
      return;
    }
    long sz = in_sizes[i];
    if (sz != elems[i] && sz != elems[i] * 2 && sz != elems[i] * 4) {
      diag(3.0e6f + (float)i * 1.25e5f);
      return;
    }
  }
  if (ws_size < need(1)) {
    diag(9.0e6f);
    return;
  }
  // -----------------------------------------------------------------------

  int* flag = (int*)ws;
  float* stats = (float*)(ws + 256);  // 128 floats: [64]{sum,sumsq}
  char* wgt = ws + 2048;
  u16* wq16 = (u16*)wgt;                   // 1572864 B
  u16* bq16 = (u16*)(wgt + 1572864);       // 2048 B
  u16* mkv16 = (u16*)(wgt + 1574912);      // [4][768][384] = 2359296 B
  u16* po16 = (u16*)(wgt + 3934208);       // 1179648 B
  float* kwf = (float*)(wgt + 5113856);    // 110592 B (f32)
  float* vwf = (float*)(wgt + 5224448);    // 110592 B (f32)
  u16* q16 = (u16*)(ws + 5337088);         // 12582912 B, persistent

  int Z = 1;
  for (int cand = 64; cand >= 1; cand >>= 1) {
    if (ws_size >= need(cand)) {
      Z = cand;
      break;
    }
  }

  char* regA = ws + bigOff;                          // Z*786432 B
  char* regB = regA + (size_t)Z * 786432;            // Z*1572864 B
  char* regC = regB + (size_t)Z * 1572864;           // Z*786432 B

  u16* text16 = (u16*)regA;  // pre-loop only; spans regA.. (9437184 B)
  u16* xT = (u16*)regA;      // then kAll, then W
  u16* kAll = (u16*)regA;
  u16* W = (u16*)regA;       // Z*294912 B (within regA)
  u16* kvpre = (u16*)regB;   // then vT | (S -> PT)
  u16* vT = (u16*)regB;
  float* S = (float*)(regB + (size_t)Z * 786432);
  u16* PT = (u16*)(regB + (size_t)Z * 786432);  // overwrites S (dead)
  u16* vAll = (u16*)regC;    // then P16
  u16* P16 = (u16*)regC;

  const float scale = 0.05103103630798288f;  // 1/sqrt(384)

  detect_dtype<<<1, blk, 0, stream>>>((const u16*)d_in[4], flag, stats);

  // 14 conversion slices. mkv16 per-branch stride = 294912 ELEMENTS.
  Cvt16 ca{};
  int ci = 0;
  auto add = [&](const void* s, u16* d, long soff, int n, int fmt) {
    ca.c[ci].s = s; ca.c[ci].d = d; ca.c[ci].soff = soff; ca.c[ci].n = n;
    ca.c[ci].fmt = fmt; ci++;
  };
  add(d_in[4], text16, 0, 4718592, 0);
  add(d_in[5], wq16, 0, 786432, 0);
  add(d_in[6], bq16, 0, 1024, 0);
  for (int i = 0; i < 4; i++)
    add(d_in[7], mkv16 + (long)i * 294912, (long)i * 147456, 147456, 0);
  for (int i = 0; i < 4; i++)
    add(d_in[8], mkv16 + (long)i * 294912 + 147456, (long)i * 147456, 147456, 0);
  add(d_in[9], (u16*)kwf, 0, 27648, 1);
  add(d_in[10], (u16*)vwf, 0, 27648, 1);
  add(d_in[11], po16, 0, 589824, 0);
  convert16<<<dim3(2304, 14, 1), blk, 0, stream>>>(ca, flag);

  // q = l2norm(text @ wq^T + bq): M=6144, N=1024, K=768
  gemm_nt<1, 1, 0><<<dim3(8, 48, 1), blk, 0, stream>>>(
      text16, wq16, q16, bq16, 768, 768, 1024, 768, 0, 0, 0, 0, 0, 0, 1.f,
      nullptr, nullptr, 0, 0, 0);
  l2norm_rows_bf16<<<6144, blk, 0, stream>>>(q16);

  Ptr4 p4 = {{d_in[0], d_in[1], d_in[2], d_in[3]}};

  for (int z0 = 0; z0 < 64; z0 += Z) {
    // xT[zl] = emb[br][b]^T
    transpose_any4<<<dim3(16, 6, Z), blk, 0, stream>>>(p4, xT, flag, z0);

    // kvpre[zl] = [mk_br; mv_br] @ x[zl] : M=768, N=1024, K=384
    gemm_nt<1, 0, 0><<<dim3(8, 6, Z), blk, 0, stream>>>(
        mkv16, xT, kvpre, nullptr, 384, 384, 1024, 384, 294912, 4, 3, 393216,
        786432, 0, 1.f, nullptr, nullptr, z0, 1, 0);

    // grouped 3x3 conv (paired outputs, padded-LDS); k gets fused L2-norm
    gconv3x3<<<dim3(192, Z, 2), blk, 0, stream>>>(kvpre, kwf, vwf, kAll,
                                                  vAll, z0);

    // vT[zl] = v[zl]^T
    transpose_bf16<<<dim3(16, 6, Z), blk, 0, stream>>>(vAll, vT);

    // S[zl] = scale * q[b] @ k[zl]^T (M=N=384, K=1024) + fused stats
    gemm_nt<0, 0, 1><<<dim3(3, 3, Z), blk, 0, stream>>>(
        q16, kAll, S, nullptr, 1024, 1024, 384, 1024, 393216, 0, 15, 393216,
        147456, 0, scale, nullptr, stats, z0, 1, 0);

    // softmax(inst-norm(S)) -> P16 (rstd inline from stats)
    softmax384<<<Z * 96, blk, 0, stream>>>(S, stats, P16, z0);

    // PT[zl] = P[zl]^T (overwrites S, dead)
    transpose_b384<<<dim3(6, 6, Z), blk, 0, stream>>>(P16, PT);

    // W[zl] = po_br @ P[zl] : M=N=K=384 (NT, B=PT) -> bf16
    gemm_nt<1, 0, 0><<<dim3(3, 3, Z), blk, 0, stream>>>(
        po16, PT, W, nullptr, 384, 384, 384, 384, 147456, 4, 3, 147456,
        147456, 0, 1.f, nullptr, nullptr, z0, 1, 0);

    // out[zg] = W[zl] @ v[zl] : M=384, N=1024, K=384 (NT, B=vT); dtype per flag
    gemm_nt<0, 0, 0><<<dim3(8, 3, Z), blk, 0, stream>>>(
        W, vT, d_out, nullptr, 384, 384, 1024, 384, 147456, 0, 63, 393216,
        393216, 0, 1.f, flag, nullptr, z0, 0, 1);
  }
}